// Round 3
// baseline (137.370 us; speedup 1.0000x reference)
//
#include <hip/hip_runtime.h>
#include <math.h>

#define D_DIM 160
#define H_DIM 192
#define W_DIM 192
#define HWN   (H_DIM * W_DIM)                 // 36864
#define NTOT  ((size_t)D_DIM * H_DIM * W_DIM) // 5898240

#define C1 0.0001f   // 0.01^2
#define C2 0.0009f   // 0.03^2

#define HSEG 24                // output rows per wave
#define NHSEG (H_DIM / HSEG)   // 8
#define NWAVES (NHSEG * 3 * D_DIM) // 3840
#define MARCH (HSEG + 10)      // 34 input rows per wave

#define DC 22                  // pass2 d-outputs per block
#define DCHUNKS 8              // 8*22 = 176 >= 160

struct GaussW { float g[11]; };

// Pass 1 v2: products + W-blur (LDS row buffer) + H-blur (rolling register
// ring). Each wave independent: owns (d, w-tile of 64, h-segment of 24).
// LDS = one 74-float row (x,y) per wave. No __syncthreads.
__global__ __launch_bounds__(256) void ssim_pass1(
    const float* __restrict__ img1, const float* __restrict__ img2,
    float* __restrict__ fields, GaussW gw)
{
    __shared__ float sx[4][80];
    __shared__ float sy[4][80];

    const int wv   = threadIdx.x >> 6;
    const int lane = threadIdx.x & 63;
    const int wid  = blockIdx.x * 4 + wv;
    const int hseg = wid & (NHSEG - 1);
    const int t    = wid >> 3;
    const int wtile = t % 3;
    const int d     = t / 3;
    const int w0    = wtile * 64;
    const int hbase = hseg * HSEG;

    const float* b1 = img1 + (size_t)d * HWN;
    const float* b2 = img2 + (size_t)d * HWN;

    // rolling ring: pending output rows, 5 fields x 11 slots, static idx only
    float acc0[11], acc1[11], acc2[11], acc3[11], acc4[11];
#pragma unroll
    for (int i = 0; i < 11; ++i) {
        acc0[i] = 0.f; acc1[i] = 0.f; acc2[i] = 0.f; acc3[i] = 0.f; acc4[i] = 0.f;
    }

    const int  wa = w0 - 5 + lane;                 // stage col 1
    const bool va = (wa >= 0) && (wa < W_DIM);
    const int  wb = w0 + 59 + lane;                // stage col 2 (lane<10)
    const bool vb = (lane < 10) && (wb < W_DIM);

    float* sxr = sx[wv];
    float* syr = sy[wv];

#pragma unroll
    for (int j = 0; j < MARCH; ++j) {
        const int  hin = hbase - 5 + j;
        const bool hok = (hin >= 0) && (hin < H_DIM);   // wave-uniform
        if (hok) {
            const float* r1 = b1 + hin * W_DIM;
            const float* r2 = b2 + hin * W_DIM;
            sxr[lane] = va ? r1[wa] : 0.f;
            syr[lane] = va ? r2[wa] : 0.f;
            if (lane < 10) {
                sxr[64 + lane] = vb ? r1[wb] : 0.f;
                syr[64 + lane] = vb ? r2[wb] : 0.f;
            }
            __builtin_amdgcn_wave_barrier();

            // W-blur of the 5 products for this row
            float a0 = 0.f, a1 = 0.f, a2 = 0.f, a3 = 0.f, a4 = 0.f;
#pragma unroll
            for (int k = 0; k < 11; ++k) {
                float x  = sxr[lane + k];
                float y  = syr[lane + k];
                float t1 = gw.g[k] * x;
                float t2 = gw.g[k] * y;
                a0 += t1;
                a1 += t2;
                a2 = fmaf(t1, x, a2);
                a3 = fmaf(t2, y, a3);
                a4 = fmaf(t1, y, a4);
            }
            __builtin_amdgcn_wave_barrier();

            // H accumulate: row j feeds outputs o = j-10..j with weight g[j-o]
#pragma unroll
            for (int tt = 0; tt < 11; ++tt) {
                const int o = j - 10 + tt;
                if (o < 0 || o >= HSEG) continue;       // compile-time pruned
                const int   s   = o % 11;
                const float wgt = gw.g[10 - tt];
                acc0[s] = fmaf(wgt, a0, acc0[s]);
                acc1[s] = fmaf(wgt, a1, acc1[s]);
                acc2[s] = fmaf(wgt, a2, acc2[s]);
                acc3[s] = fmaf(wgt, a3, acc3[s]);
                acc4[s] = fmaf(wgt, a4, acc4[s]);
            }
        }
        // emit completed output row o = j-10
        if (j >= 10) {
            const int o = j - 10;                       // 0..23
            const int s = o % 11;
            const int hout = hbase + o;
            size_t base = (size_t)d * HWN + (size_t)hout * W_DIM + (w0 + lane);
            fields[base]            = acc0[s];
            fields[NTOT + base]     = acc1[s];
            fields[2 * NTOT + base] = acc2[s];
            fields[3 * NTOT + base] = acc3[s];
            fields[4 * NTOT + base] = acc4[s];
            acc0[s] = 0.f; acc1[s] = 0.f; acc2[s] = 0.f; acc3[s] = 0.f; acc4[s] = 0.f;
        }
    }
}

// Pass 2: rolling-window D-blur + SSIM + block reduce -> double atomic.
__global__ __launch_bounds__(256) void ssim_pass2(
    const float* __restrict__ fields, double* __restrict__ accum, GaussW gwts)
{
    const int hw = blockIdx.x * 256 + threadIdx.x;
    const int d0 = blockIdx.y * DC;

    float win[5][11];
#pragma unroll
    for (int i = 0; i < 10; ++i) {
        int p = d0 - 5 + i;
        bool ok = (p >= 0) && (p < D_DIM);
        size_t off = (size_t)(ok ? p : 0) * HWN + hw;
#pragma unroll
        for (int f = 0; f < 5; ++f)
            win[f][i] = ok ? fields[(size_t)f * NTOT + off] : 0.f;
    }

    float ssum = 0.f;
#pragma unroll
    for (int j = 0; j < DC; ++j) {
        const int d = d0 + j;
        {
            int p = d + 5;
            bool ok = (p < D_DIM);
            size_t off = (size_t)(ok ? p : 0) * HWN + hw;
#pragma unroll
            for (int f = 0; f < 5; ++f)
                win[f][(j + 10) % 11] = ok ? fields[(size_t)f * NTOT + off] : 0.f;
        }
        if (d < D_DIM) {
            float m[5];
#pragma unroll
            for (int f = 0; f < 5; ++f) {
                float acc = 0.f;
#pragma unroll
                for (int k = 0; k < 11; ++k)
                    acc += gwts.g[k] * win[f][(j + k) % 11];
                m[f] = acc;
            }
            float mu1sq = m[0] * m[0];
            float mu2sq = m[1] * m[1];
            float mu12  = m[0] * m[1];
            float s1sq  = m[2] - mu1sq;
            float s2sq  = m[3] - mu2sq;
            float s12   = m[4] - mu12;
            ssum += ((2.f * mu12 + C1) * (2.f * s12 + C2)) /
                    ((mu1sq + mu2sq + C1) * (s1sq + s2sq + C2));
        }
    }

    for (int off = 32; off > 0; off >>= 1)
        ssum += __shfl_down(ssum, off, 64);
    __shared__ float wsum[4];
    int lane = threadIdx.x & 63;
    int wvx  = threadIdx.x >> 6;
    if (lane == 0) wsum[wvx] = ssum;
    __syncthreads();
    if (threadIdx.x == 0) {
        float bs = wsum[0] + wsum[1] + wsum[2] + wsum[3];
        atomicAdd(accum, (double)bs);
    }
}

__global__ void ssim_finalize(const double* __restrict__ accum,
                              float* __restrict__ out)
{
    out[0] = (float)(accum[0] / (double)NTOT);
}

extern "C" void kernel_launch(void* const* d_in, const int* in_sizes, int n_in,
                              void* d_out, int out_size, void* d_ws, size_t ws_size,
                              hipStream_t stream)
{
    const float* img1 = (const float*)d_in[0];
    const float* img2 = (const float*)d_in[1];
    float* out = (float*)d_out;

    GaussW gwts;
    {
        double raw[11], sum = 0.0;
        for (int i = 0; i < 11; ++i) {
            double x = (double)i - 5.0;
            raw[i] = exp(-(x * x) / (2.0 * 1.5 * 1.5));
            sum += raw[i];
        }
        for (int i = 0; i < 11; ++i) gwts.g[i] = (float)(raw[i] / sum);
    }

    float* fields = (float*)d_ws;                          // 5 * NTOT floats
    double* accum = (double*)((char*)d_ws + 5 * NTOT * 4); // 8B, 8-aligned

    hipMemsetAsync(accum, 0, sizeof(double), stream);

    ssim_pass1<<<NWAVES / 4, 256, 0, stream>>>(img1, img2, fields, gwts);

    dim3 g2(HWN / 256, DCHUNKS); // (144, 8)
    ssim_pass2<<<g2, 256, 0, stream>>>(fields, accum, gwts);

    ssim_finalize<<<1, 1, 0, stream>>>(accum, out);
}

// Round 4
// 99.645 us; speedup vs baseline: 1.3786x; 1.3786x over previous
//
#include <hip/hip_runtime.h>
#include <math.h>

#define D_DIM 160
#define H_DIM 192
#define W_DIM 192
#define HWN   (H_DIM * W_DIM)                 // 36864
#define NTOT  ((size_t)D_DIM * H_DIM * W_DIM) // 5898240

#define C1 0.0001f   // 0.01^2
#define C2 0.0009f   // 0.03^2

#define HSEG 24                // output rows per wave
#define NHSEG (H_DIM / HSEG)   // 8
#define NWAVES (NHSEG * 3 * D_DIM) // 3840
#define MARCH (HSEG + 10)      // 34 input rows per wave

#define DC 22                  // pass2 d-outputs per block
#define DCHUNKS 8              // 8*22 = 176 >= 160

struct GaussW { float g[11]; };

// Pass 1 v3: products + W-blur (float2 LDS row buffer) + H-blur via
// SHIFT-REGISTER ring (all indices static even in a rolled loop -> VGPRs).
// Each wave independent: owns (d, w-tile of 64, h-segment of 24).
__global__ __launch_bounds__(256) void ssim_pass1(
    const float* __restrict__ img1, const float* __restrict__ img2,
    float* __restrict__ fields, GaussW gw)
{
    __shared__ float2 sxy[4][80];

    const int wv   = threadIdx.x >> 6;
    const int lane = threadIdx.x & 63;
    const int wid  = blockIdx.x * 4 + wv;
    const int hseg = wid & (NHSEG - 1);
    const int t    = wid >> 3;
    const int wtile = t % 3;
    const int d     = t / 3;
    const int w0    = wtile * 64;
    const int hbase = hseg * HSEG;

    // row pointers, marching with += W_DIM
    const float* rp1 = img1 + (size_t)d * HWN + (long)(hbase - 5) * W_DIM;
    const float* rp2 = img2 + (size_t)d * HWN + (long)(hbase - 5) * W_DIM;

    // shift-register ring: acc[i] accumulates output row (j-10)+i
    float acc0[11], acc1[11], acc2[11], acc3[11], acc4[11];
#pragma unroll
    for (int i = 0; i < 11; ++i) {
        acc0[i] = 0.f; acc1[i] = 0.f; acc2[i] = 0.f; acc3[i] = 0.f; acc4[i] = 0.f;
    }

    const int  cola = w0 - 5 + lane;                // stage col 1
    const bool va   = (cola >= 0) && (cola < W_DIM);
    const int  colb = w0 + 59 + lane;               // stage col 2 (lane<10)
    const bool vb   = (lane < 10) && (colb < W_DIM);

    float2* srow = sxy[wv];

    // emit pointer (field 0); other fields at +f*NTOT
    float* ep = fields + (size_t)d * HWN + (size_t)hbase * W_DIM + (w0 + lane);

    for (int j = 0; j < MARCH; ++j) {
        const int hin = hbase - 5 + j;
        if (hin >= 0 && hin < H_DIM) {              // wave-uniform
            float2 v;
            v.x = va ? rp1[cola] : 0.f;
            v.y = va ? rp2[cola] : 0.f;
            srow[lane] = v;
            if (lane < 10) {
                float2 u;
                u.x = vb ? rp1[colb] : 0.f;
                u.y = vb ? rp2[colb] : 0.f;
                srow[64 + lane] = u;
            }
            __builtin_amdgcn_wave_barrier();

            // W-blur of the 5 products for this row
            float a0 = 0.f, a1 = 0.f, a2 = 0.f, a3 = 0.f, a4 = 0.f;
#pragma unroll
            for (int k = 0; k < 11; ++k) {
                float2 p = srow[lane + k];
                float t1 = gw.g[k] * p.x;
                float t2 = gw.g[k] * p.y;
                a0 += t1;
                a1 += t2;
                a2 = fmaf(t1, p.x, a2);
                a3 = fmaf(t2, p.y, a3);
                a4 = fmaf(t1, p.y, a4);
            }
            __builtin_amdgcn_wave_barrier();

            // H accumulate into shift ring (static indices)
#pragma unroll
            for (int i = 0; i < 11; ++i) {
                const float wgt = gw.g[10 - i];
                acc0[i] = fmaf(wgt, a0, acc0[i]);
                acc1[i] = fmaf(wgt, a1, acc1[i]);
                acc2[i] = fmaf(wgt, a2, acc2[i]);
                acc3[i] = fmaf(wgt, a3, acc3[i]);
                acc4[i] = fmaf(wgt, a4, acc4[i]);
            }
        }
        rp1 += W_DIM;
        rp2 += W_DIM;

        // emit completed output row o = j-10 (always < HSEG)
        if (j >= 10) {
            ep[0]        = acc0[0];
            ep[NTOT]     = acc1[0];
            ep[2 * NTOT] = acc2[0];
            ep[3 * NTOT] = acc3[0];
            ep[4 * NTOT] = acc4[0];
            ep += W_DIM;
        }

        // shift ring down (static indices)
#pragma unroll
        for (int i = 0; i < 10; ++i) {
            acc0[i] = acc0[i + 1];
            acc1[i] = acc1[i + 1];
            acc2[i] = acc2[i + 1];
            acc3[i] = acc3[i + 1];
            acc4[i] = acc4[i + 1];
        }
        acc0[10] = 0.f; acc1[10] = 0.f; acc2[10] = 0.f; acc3[10] = 0.f; acc4[10] = 0.f;
    }
}

// Pass 2: rolling-window D-blur + SSIM + block reduce -> double atomic.
__global__ __launch_bounds__(256) void ssim_pass2(
    const float* __restrict__ fields, double* __restrict__ accum, GaussW gwts)
{
    const int hw = blockIdx.x * 256 + threadIdx.x;
    const int d0 = blockIdx.y * DC;

    float win[5][11];
#pragma unroll
    for (int i = 0; i < 10; ++i) {
        int p = d0 - 5 + i;
        bool ok = (p >= 0) && (p < D_DIM);
        size_t off = (size_t)(ok ? p : 0) * HWN + hw;
#pragma unroll
        for (int f = 0; f < 5; ++f)
            win[f][i] = ok ? fields[(size_t)f * NTOT + off] : 0.f;
    }

    float ssum = 0.f;
#pragma unroll
    for (int j = 0; j < DC; ++j) {
        const int d = d0 + j;
        {
            int p = d + 5;
            bool ok = (p < D_DIM);
            size_t off = (size_t)(ok ? p : 0) * HWN + hw;
#pragma unroll
            for (int f = 0; f < 5; ++f)
                win[f][(j + 10) % 11] = ok ? fields[(size_t)f * NTOT + off] : 0.f;
        }
        if (d < D_DIM) {
            float m[5];
#pragma unroll
            for (int f = 0; f < 5; ++f) {
                float acc = 0.f;
#pragma unroll
                for (int k = 0; k < 11; ++k)
                    acc += gwts.g[k] * win[f][(j + k) % 11];
                m[f] = acc;
            }
            float mu1sq = m[0] * m[0];
            float mu2sq = m[1] * m[1];
            float mu12  = m[0] * m[1];
            float s1sq  = m[2] - mu1sq;
            float s2sq  = m[3] - mu2sq;
            float s12   = m[4] - mu12;
            ssum += ((2.f * mu12 + C1) * (2.f * s12 + C2)) /
                    ((mu1sq + mu2sq + C1) * (s1sq + s2sq + C2));
        }
    }

    for (int off = 32; off > 0; off >>= 1)
        ssum += __shfl_down(ssum, off, 64);
    __shared__ float wsum[4];
    int lane = threadIdx.x & 63;
    int wvx  = threadIdx.x >> 6;
    if (lane == 0) wsum[wvx] = ssum;
    __syncthreads();
    if (threadIdx.x == 0) {
        float bs = wsum[0] + wsum[1] + wsum[2] + wsum[3];
        atomicAdd(accum, (double)bs);
    }
}

__global__ void ssim_finalize(const double* __restrict__ accum,
                              float* __restrict__ out)
{
    out[0] = (float)(accum[0] / (double)NTOT);
}

extern "C" void kernel_launch(void* const* d_in, const int* in_sizes, int n_in,
                              void* d_out, int out_size, void* d_ws, size_t ws_size,
                              hipStream_t stream)
{
    const float* img1 = (const float*)d_in[0];
    const float* img2 = (const float*)d_in[1];
    float* out = (float*)d_out;

    GaussW gwts;
    {
        double raw[11], sum = 0.0;
        for (int i = 0; i < 11; ++i) {
            double x = (double)i - 5.0;
            raw[i] = exp(-(x * x) / (2.0 * 1.5 * 1.5));
            sum += raw[i];
        }
        for (int i = 0; i < 11; ++i) gwts.g[i] = (float)(raw[i] / sum);
    }

    float* fields = (float*)d_ws;                          // 5 * NTOT floats
    double* accum = (double*)((char*)d_ws + 5 * NTOT * 4); // 8B, 8-aligned

    hipMemsetAsync(accum, 0, sizeof(double), stream);

    ssim_pass1<<<NWAVES / 4, 256, 0, stream>>>(img1, img2, fields, gwts);

    dim3 g2(HWN / 256, DCHUNKS); // (144, 8)
    ssim_pass2<<<g2, 256, 0, stream>>>(fields, accum, gwts);

    ssim_finalize<<<1, 1, 0, stream>>>(accum, out);
}

// Round 5
// 97.716 us; speedup vs baseline: 1.4058x; 1.0197x over previous
//
#include <hip/hip_runtime.h>
#include <math.h>

#define D_DIM 160
#define H_DIM 192
#define W_DIM 192
#define HWN   (H_DIM * W_DIM)                 // 36864
#define NTOT  ((size_t)D_DIM * H_DIM * W_DIM) // 5898240

#define C1 0.0001f   // 0.01^2
#define C2 0.0009f   // 0.03^2

#define HSEG 24                // output rows per wave
#define NHSEG (H_DIM / HSEG)   // 8
#define NWAVES (NHSEG * 3 * D_DIM) // 3840
#define MARCH (HSEG + 10)      // 34 input rows per wave

#define DC 22                  // pass2 d-outputs per block
#define DCHUNKS 8              // 8*22 = 176 >= 160

struct GaussW { float g[11]; };

// ---- named-scalar shift ring (NO arrays -> guaranteed SSA/VGPR) ----
#define DECL_RING(A) \
    float A##0=0.f,A##1=0.f,A##2=0.f,A##3=0.f,A##4=0.f,A##5=0.f, \
          A##6=0.f,A##7=0.f,A##8=0.f,A##9=0.f,A##10=0.f

// slot i holds output row (j-10)+i; row j contributes weight g[10-i] to slot i
#define ACCUM_RING(A, v) do { \
    A##0  = fmaf(gw.g[10], (v), A##0);  \
    A##1  = fmaf(gw.g[9],  (v), A##1);  \
    A##2  = fmaf(gw.g[8],  (v), A##2);  \
    A##3  = fmaf(gw.g[7],  (v), A##3);  \
    A##4  = fmaf(gw.g[6],  (v), A##4);  \
    A##5  = fmaf(gw.g[5],  (v), A##5);  \
    A##6  = fmaf(gw.g[4],  (v), A##6);  \
    A##7  = fmaf(gw.g[3],  (v), A##7);  \
    A##8  = fmaf(gw.g[2],  (v), A##8);  \
    A##9  = fmaf(gw.g[1],  (v), A##9);  \
    A##10 = fmaf(gw.g[0],  (v), A##10); } while (0)

#define SHIFT_RING(A) do { \
    A##0=A##1; A##1=A##2; A##2=A##3; A##3=A##4; A##4=A##5; A##5=A##6; \
    A##6=A##7; A##7=A##8; A##8=A##9; A##9=A##10; A##10=0.f; } while (0)

// Pass 1 v4: products + W-blur (float2 LDS row buffer) + H-blur via
// named-scalar shift ring. Each wave independent: (d, w-tile 64, h-seg 24).
__global__ __launch_bounds__(256, 2) void ssim_pass1(
    const float* __restrict__ img1, const float* __restrict__ img2,
    float* __restrict__ fields, GaussW gw)
{
    __shared__ float2 sxy[4][80];

    const int wv   = threadIdx.x >> 6;
    const int lane = threadIdx.x & 63;
    const int wid  = blockIdx.x * 4 + wv;
    const int hseg = wid & (NHSEG - 1);
    const int t    = wid >> 3;
    const int wtile = t % 3;
    const int d     = t / 3;
    const int w0    = wtile * 64;
    const int hbase = hseg * HSEG;

    const float* rp1 = img1 + (size_t)d * HWN + (long)(hbase - 5) * W_DIM;
    const float* rp2 = img2 + (size_t)d * HWN + (long)(hbase - 5) * W_DIM;

    DECL_RING(r0); DECL_RING(r1); DECL_RING(r2); DECL_RING(r3); DECL_RING(r4);

    const int  cola = w0 - 5 + lane;                // stage col 1
    const bool va   = (cola >= 0) && (cola < W_DIM);
    const int  colb = w0 + 59 + lane;               // stage col 2 (lane<10)
    const bool vb   = (lane < 10) && (colb < W_DIM);

    float2* srow = sxy[wv];

    float* ep = fields + (size_t)d * HWN + (size_t)hbase * W_DIM + (w0 + lane);

    for (int j = 0; j < MARCH; ++j) {
        const int hin = hbase - 5 + j;
        if (hin >= 0 && hin < H_DIM) {              // wave-uniform
            float2 v;
            v.x = va ? rp1[cola] : 0.f;
            v.y = va ? rp2[cola] : 0.f;
            srow[lane] = v;
            if (lane < 10) {
                float2 u;
                u.x = vb ? rp1[colb] : 0.f;
                u.y = vb ? rp2[colb] : 0.f;
                srow[64 + lane] = u;
            }
            __builtin_amdgcn_wave_barrier();

            // W-blur of the 5 products for this row
            float a0 = 0.f, a1 = 0.f, a2 = 0.f, a3 = 0.f, a4 = 0.f;
#pragma unroll
            for (int k = 0; k < 11; ++k) {
                float2 p = srow[lane + k];
                float t1 = gw.g[k] * p.x;
                float t2 = gw.g[k] * p.y;
                a0 += t1;
                a1 += t2;
                a2 = fmaf(t1, p.x, a2);
                a3 = fmaf(t2, p.y, a3);
                a4 = fmaf(t1, p.y, a4);
            }
            __builtin_amdgcn_wave_barrier();

            ACCUM_RING(r0, a0);
            ACCUM_RING(r1, a1);
            ACCUM_RING(r2, a2);
            ACCUM_RING(r3, a3);
            ACCUM_RING(r4, a4);
        }
        rp1 += W_DIM;
        rp2 += W_DIM;

        // emit completed output row o = j-10 (slot 0), then shift
        if (j >= 10) {
            ep[0]        = r00;
            ep[NTOT]     = r10;
            ep[2 * NTOT] = r20;
            ep[3 * NTOT] = r30;
            ep[4 * NTOT] = r40;
            ep += W_DIM;
        }
        SHIFT_RING(r0); SHIFT_RING(r1); SHIFT_RING(r2);
        SHIFT_RING(r3); SHIFT_RING(r4);
    }
}

// Pass 2: rolling-window D-blur + SSIM + block reduce -> double atomic.
__global__ __launch_bounds__(256) void ssim_pass2(
    const float* __restrict__ fields, double* __restrict__ accum, GaussW gwts)
{
    const int hw = blockIdx.x * 256 + threadIdx.x;
    const int d0 = blockIdx.y * DC;

    float win[5][11];
#pragma unroll
    for (int i = 0; i < 10; ++i) {
        int p = d0 - 5 + i;
        bool ok = (p >= 0) && (p < D_DIM);
        size_t off = (size_t)(ok ? p : 0) * HWN + hw;
#pragma unroll
        for (int f = 0; f < 5; ++f)
            win[f][i] = ok ? fields[(size_t)f * NTOT + off] : 0.f;
    }

    float ssum = 0.f;
#pragma unroll
    for (int j = 0; j < DC; ++j) {
        const int d = d0 + j;
        {
            int p = d + 5;
            bool ok = (p < D_DIM);
            size_t off = (size_t)(ok ? p : 0) * HWN + hw;
#pragma unroll
            for (int f = 0; f < 5; ++f)
                win[f][(j + 10) % 11] = ok ? fields[(size_t)f * NTOT + off] : 0.f;
        }
        if (d < D_DIM) {
            float m[5];
#pragma unroll
            for (int f = 0; f < 5; ++f) {
                float acc = 0.f;
#pragma unroll
                for (int k = 0; k < 11; ++k)
                    acc += gwts.g[k] * win[f][(j + k) % 11];
                m[f] = acc;
            }
            float mu1sq = m[0] * m[0];
            float mu2sq = m[1] * m[1];
            float mu12  = m[0] * m[1];
            float s1sq  = m[2] - mu1sq;
            float s2sq  = m[3] - mu2sq;
            float s12   = m[4] - mu12;
            ssum += ((2.f * mu12 + C1) * (2.f * s12 + C2)) /
                    ((mu1sq + mu2sq + C1) * (s1sq + s2sq + C2));
        }
    }

    for (int off = 32; off > 0; off >>= 1)
        ssum += __shfl_down(ssum, off, 64);
    __shared__ float wsum[4];
    int lane = threadIdx.x & 63;
    int wvx  = threadIdx.x >> 6;
    if (lane == 0) wsum[wvx] = ssum;
    __syncthreads();
    if (threadIdx.x == 0) {
        float bs = wsum[0] + wsum[1] + wsum[2] + wsum[3];
        atomicAdd(accum, (double)bs);
    }
}

__global__ void ssim_finalize(const double* __restrict__ accum,
                              float* __restrict__ out)
{
    out[0] = (float)(accum[0] / (double)NTOT);
}

extern "C" void kernel_launch(void* const* d_in, const int* in_sizes, int n_in,
                              void* d_out, int out_size, void* d_ws, size_t ws_size,
                              hipStream_t stream)
{
    const float* img1 = (const float*)d_in[0];
    const float* img2 = (const float*)d_in[1];
    float* out = (float*)d_out;

    GaussW gwts;
    {
        double raw[11], sum = 0.0;
        for (int i = 0; i < 11; ++i) {
            double x = (double)i - 5.0;
            raw[i] = exp(-(x * x) / (2.0 * 1.5 * 1.5));
            sum += raw[i];
        }
        for (int i = 0; i < 11; ++i) gwts.g[i] = (float)(raw[i] / sum);
    }

    float* fields = (float*)d_ws;                          // 5 * NTOT floats
    double* accum = (double*)((char*)d_ws + 5 * NTOT * 4); // 8B, 8-aligned

    hipMemsetAsync(accum, 0, sizeof(double), stream);

    ssim_pass1<<<NWAVES / 4, 256, 0, stream>>>(img1, img2, fields, gwts);

    dim3 g2(HWN / 256, DCHUNKS); // (144, 8)
    ssim_pass2<<<g2, 256, 0, stream>>>(fields, accum, gwts);

    ssim_finalize<<<1, 1, 0, stream>>>(accum, out);
}